// Round 8
// baseline (477.533 us; speedup 1.0000x reference)
//
#include <hip/hip_runtime.h>

#define BATCH 16
#define CIN 512
#define NPIX 4096

typedef __attribute__((ext_vector_type(8))) short bf16x8;
typedef __attribute__((ext_vector_type(4))) float f32x4;

#define MFMA(a,b,c) __builtin_amdgcn_mfma_f32_16x16x32_bf16((a),(b),(c),0,0,0)

union PK  { short s[8]; bf16x8 v; };
union PK4 { short s[4]; uint2 u; };

__device__ __forceinline__ unsigned short bf16_rne(float f){
  unsigned u = __float_as_uint(f);
  return (unsigned short)((u + 0x7fffu + ((u >> 16) & 1u)) >> 16);
}
__device__ __forceinline__ void f32_split(float f, short &h, short &l){
  unsigned short hu = bf16_rne(f);
  h = (short)hu;
  float fh = __uint_as_float((unsigned)hu << 16);
  l = (short)bf16_rne(f - fh);
}
__device__ __forceinline__ void split8(float4 a, float4 b, bf16x8 &h, bf16x8 &l){
  float vv[8] = {a.x,a.y,a.z,a.w,b.x,b.y,b.z,b.w};
  PK ph, pl;
  #pragma unroll
  for (int z=0;z<8;z++){ short hh,ll; f32_split(vv[z],hh,ll); ph.s[z]=hh; pl.s[z]=ll; }
  h = ph.v; l = pl.v;
}

// chunk-XOR swizzle within a 512-short row: (row,k) -> row*512 + slot*8 + (k&7)
__device__ __forceinline__ int offBig(int row, int k){
  int s = k >> 3;
  s = (s & ~7) | ((s ^ row) & 7);
  return row*512 + s*8 + (k & 7);
}

// ---------------- weight convert ----------------
// WG  [512][512] bf16: row 2o = Wq[o], 2o+1 = Wk[o]
// WSE [128][512] bf16: rows 0-63 Ws, 64-127 We ; WSL [64][512] lo of Ws
__global__ __launch_bounds__(256)
void k_convw(const float* __restrict__ Wq, const float* __restrict__ bq,
             const float* __restrict__ Wk, const float* __restrict__ bk,
             const float* __restrict__ Ws, const float* __restrict__ bs,
             const float* __restrict__ We, const float* __restrict__ be,
             short* __restrict__ WG, short* __restrict__ WSE, short* __restrict__ WSL,
             float* __restrict__ BG, float* __restrict__ BSE){
  int t = blockIdx.x*256 + threadIdx.x;
  if (t < 512*512){
    int r = t >> 9, c = t & 511, o = r >> 1;
    float v = (r & 1) ? Wk[o*512+c] : Wq[o*512+c];
    WG[t] = (short)bf16_rne(v);
  }
  if (t < 128*512){
    int r = t >> 9, c = t & 511;
    float v = (r < 64) ? Ws[r*512+c] : We[(r-64)*512+c];
    short h,l; f32_split(v,h,l);
    WSE[t] = h;
    if (r < 64) WSL[t] = l;
  }
  if (t < 512) BG[t] = (t&1) ? bk[t>>1] : bq[t>>1];
  if (t < 128) BSE[t] = (t < 64) ? bs[t] : be[t-64];
}

// ---------------- fused front: gate + Qs(split,gate-folded) + Ke ----------------
// grid (32 nt, 16 b), 1024 thr (16 waves = 2 groups x 8). XS[128n][512c] staged once
// (128 KB LDS, 1 block/CU but 4 waves/SIMD -> 2x latency hiding vs R7).
// Each 8-wave group runs the R7-proven roles on its 64-n half; weight fetch shared.
__global__ __launch_bounds__(1024)
void k_front(const float* __restrict__ x, const short* __restrict__ WG,
             const float* __restrict__ BG, const short* __restrict__ WSE,
             const short* __restrict__ WSL, const float* __restrict__ BSE,
             float* __restrict__ QSG, short* __restrict__ KET, float* __restrict__ S){
  __shared__ __align__(16) short XS[128*512];  // 128 KB
  __shared__ float QKf[1024];
  __shared__ float GF[128];
  int nt = blockIdx.x, b = blockIdx.y;
  int n0 = nt*128;
  int tid = threadIdx.x, w = tid>>6, lane = tid&63;
  int wl = w & 7, wg = w >> 3;
  int n0g = n0 + wg*64;
  int lr = lane&15, lk = (lane>>4)<<3;
  bool isQs = (wl < 4);
  const short* wgb = WG  + (size_t)(wl*64 + lr)*512 + lk;
  const short* wb  = WSE + (size_t)((isQs ? (wl*16) : (64 + (wl-4)*16)) + lr)*512 + lk;
  const short* wlb = WSL + (size_t)((isQs ? (wl*16) : 0) + lr)*512 + lk;

  // stage: thread = (channel, n-half), transpose-write 64 n values
  {
    int cl = tid & 511, nh = tid >> 9;
    const float* xp = x + ((size_t)b*CIN + cl)*NPIX + n0 + nh*64;
    for (int i=0;i<64;i+=4){
      float4 v = *(const float4*)(xp + i);
      float vv[4] = {v.x, v.y, v.z, v.w};
      #pragma unroll
      for (int u=0;u<4;u++)
        XS[offBig(nh*64 + i+u, cl)] = (short)bf16_rne(vv[u]);
    }
  }
  __syncthreads();

  f32x4 acc1[4][4] = {};
  f32x4 acc2[4] = {};

  // prefetch kt=0 weight fragments into named cur registers
  bf16x8 c0 = *(const bf16x8*)(wgb + 0*16*512);
  bf16x8 c1 = *(const bf16x8*)(wgb + 1*16*512);
  bf16x8 c2 = *(const bf16x8*)(wgb + 2*16*512);
  bf16x8 c3 = *(const bf16x8*)(wgb + 3*16*512);
  bf16x8 chh = *(const bf16x8*)(wb);
  bf16x8 cll = isQs ? *(const bf16x8*)(wlb) : chh;

  for (int kt=0; kt<16; kt++){
    bf16x8 n0f=c0, n1f=c1, n2f=c2, n3f=c3, nhf=chh, nlf=cll;
    if (kt < 15){
      int o = (kt+1)*32;
      n0f = *(const bf16x8*)(wgb + 0*16*512 + o);
      n1f = *(const bf16x8*)(wgb + 1*16*512 + o);
      n2f = *(const bf16x8*)(wgb + 2*16*512 + o);
      n3f = *(const bf16x8*)(wgb + 3*16*512 + o);
      nhf = *(const bf16x8*)(wb + o);
      nlf = isQs ? *(const bf16x8*)(wlb + o) : nhf;
    }
    bf16x8 bb[4];
    #pragma unroll
    for (int j=0;j<4;j++)
      bb[j] = *(const bf16x8*)&XS[offBig(wg*64 + j*16 + lr, kt*32 + lk)];
    // proj MFMAs (Qs hi+lo / Ke hi)
    if (isQs){
      #pragma unroll
      for (int j=0;j<4;j++){
        acc2[j] = MFMA(cll, bb[j], acc2[j]);
        acc2[j] = MFMA(chh, bb[j], acc2[j]);
      }
    } else {
      #pragma unroll
      for (int j=0;j<4;j++)
        acc2[j] = MFMA(chh, bb[j], acc2[j]);
    }
    // gate MFMAs
    #pragma unroll
    for (int j=0;j<4;j++) acc1[0][j] = MFMA(c0, bb[j], acc1[0][j]);
    #pragma unroll
    for (int j=0;j<4;j++) acc1[1][j] = MFMA(c1, bb[j], acc1[1][j]);
    #pragma unroll
    for (int j=0;j<4;j++) acc1[2][j] = MFMA(c2, bb[j], acc1[2][j]);
    #pragma unroll
    for (int j=0;j<4;j++) acc1[3][j] = MFMA(c3, bb[j], acc1[3][j]);
    c0=n0f; c1=n1f; c2=n2f; c3=n3f; chh=nhf; cll=nlf;
  }

  // ---- QK reduce -> gate (per 8-wave group) ----
  int rq = (lane>>4)<<2;
  {
    float p[4] = {0.f,0.f,0.f,0.f};
    #pragma unroll
    for (int r=0;r<4;r++){
      f32x4 bg = *(const f32x4*)&BG[wl*64 + r*16 + rq];
      #pragma unroll
      for (int j=0;j<4;j++){
        f32x4 a4 = acc1[r][j];
        p[j] += (a4[0]+bg[0])*(a4[1]+bg[1]) + (a4[2]+bg[2])*(a4[3]+bg[3]);
      }
    }
    #pragma unroll
    for (int j=0;j<4;j++){ p[j] += __shfl_xor(p[j],16); p[j] += __shfl_xor(p[j],32); }
    if (lane < 16){
      #pragma unroll
      for (int j=0;j<4;j++) QKf[wg*512 + wl*64 + j*16 + lane] = p[j];
    }
  }
  __syncthreads();
  if (tid < 128){
    int h = tid >> 6, nl = tid & 63;
    float s = 0.f;
    #pragma unroll
    for (int ww=0;ww<8;ww++) s += QKf[h*512 + ww*64 + nl];
    GF[h*64 + nl] = 1.f/(1.f + __expf(-s*(1.f/256.f)));
  }
  __syncthreads();

  // ---- epilogue ----
  if (isQs){
    int row0 = wl*16 + rq;
    f32x4 bs4 = *(const f32x4*)&BSE[row0];
    float srow[4] = {0.f,0.f,0.f,0.f};
    #pragma unroll
    for (int j=0;j<4;j++){
      int nl = j*16 + lr;
      float g = GF[wg*64 + nl];
      int n = n0g + nl;
      #pragma unroll
      for (int q=0;q<4;q++){
        float v = (acc2[j][q] + bs4[q]) * g;
        QSG[((size_t)(b*64) + row0 + q)*NPIX + n] = v;
        srow[q] += v;
      }
    }
    #pragma unroll
    for (int q=0;q<4;q++){
      float v = srow[q];
      v += __shfl_xor(v,1); v += __shfl_xor(v,2);
      v += __shfl_xor(v,4); v += __shfl_xor(v,8);
      if (lr == 0) atomicAdd(&S[b*64 + row0 + q], v);
    }
  } else {
    int d0 = (wl-4)*16 + rq;
    f32x4 be4 = *(const f32x4*)&BSE[64 + d0];
    #pragma unroll
    for (int j=0;j<4;j++){
      int n = n0g + j*16 + lr;
      PK4 pk;
      #pragma unroll
      for (int q=0;q<4;q++) pk.s[q] = (short)bf16_rne(acc2[j][q] + be4[q]);
      *(uint2*)&KET[((size_t)(b*NPIX) + n)*64 + d0] = pk.u;
    }
  }
}

// ---------------- M[b][512][64] += x . QSG^T over n (reg-split, no LDS) ----------------
// 16 slabs x 256 n: halves atomic traffic vs 32 slabs.
__global__ __launch_bounds__(512)
void k_M(const float* __restrict__ x, const float* __restrict__ QSG,
         float* __restrict__ M){
  int slab = blockIdx.x, b = blockIdx.y;
  int tid = threadIdx.x, w = tid>>6, lane = tid&63;
  int lr = lane&15, lk8 = (lane>>4)<<3;
  f32x4 acc[4][4] = {};
  for (int kt=0; kt<8; kt++){
    int noff = slab*256 + kt*32 + lk8;
    bf16x8 bh[4], bl[4];
    #pragma unroll
    for (int j=0;j<4;j++){
      const float* qp = QSG + ((size_t)(b*64) + j*16 + lr)*NPIX + noff;
      split8(*(const float4*)qp, *(const float4*)(qp+4), bh[j], bl[j]);
    }
    #pragma unroll
    for (int r=0;r<4;r++){
      const float* xp = x + ((size_t)(b*CIN) + w*64 + r*16 + lr)*NPIX + noff;
      bf16x8 ah, al;
      split8(*(const float4*)xp, *(const float4*)(xp+4), ah, al);
      #pragma unroll
      for (int j=0;j<4;j++){
        acc[r][j] = MFMA(al, bh[j], acc[r][j]);
        acc[r][j] = MFMA(ah, bl[j], acc[r][j]);
        acc[r][j] = MFMA(ah, bh[j], acc[r][j]);
      }
    }
  }
  int rq = (lane>>4)<<2;
  #pragma unroll
  for (int r=0;r<4;r++)
    #pragma unroll
    for (int j=0;j<4;j++)
      #pragma unroll
      for (int q=0;q<4;q++)
        atomicAdd(&M[((size_t)(b*CIN) + w*64 + r*16 + rq + q)*64 + j*16 + lr], acc[r][j][q]);
}

// ---------------- energy = Wv(f32) . M + bv*S  (VALU, exact) ----------------
__global__ __launch_bounds__(256)
void k_energy(const float* __restrict__ Wv, const float* __restrict__ bv,
              const float* __restrict__ M, const float* __restrict__ S,
              float* __restrict__ EN){
  __shared__ __align__(16) float ML[128*68];
  int cch = blockIdx.x, b = blockIdx.y;
  int tid = threadIdx.x;
  int d4 = tid & 15, ci = tid >> 4;
  f32x4 acc[2] = {};
  for (int kt=0; kt<4; kt++){
    __syncthreads();
    for (int i = tid; i < 2048; i += 256){
      int k = i >> 4, c4 = (i & 15) * 4;
      *(float4*)&ML[k*68 + c4] = *(const float4*)&M[((size_t)(b*CIN) + kt*128 + k)*64 + c4];
    }
    __syncthreads();
    #pragma unroll
    for (int m=0;m<2;m++){
      int c = cch*32 + ci + 16*m;
      const float* wvp = Wv + (size_t)c*512 + kt*128;
      for (int k4=0;k4<32;k4++){
        float4 wv4 = *(const float4*)(wvp + k4*4);
        f32x4 m0 = *(const f32x4*)&ML[(k4*4+0)*68 + d4*4];
        f32x4 m1 = *(const f32x4*)&ML[(k4*4+1)*68 + d4*4];
        f32x4 m2 = *(const f32x4*)&ML[(k4*4+2)*68 + d4*4];
        f32x4 m3 = *(const f32x4*)&ML[(k4*4+3)*68 + d4*4];
        acc[m] += m0*wv4.x + m1*wv4.y + m2*wv4.z + m3*wv4.w;
      }
    }
  }
  f32x4 s4 = *(const f32x4*)&S[b*64 + d4*4];
  #pragma unroll
  for (int m=0;m<2;m++){
    int c = cch*32 + ci + 16*m;
    f32x4 r = acc[m] + s4*bv[c];
    *(f32x4*)&EN[((size_t)(b*CIN) + c)*64 + d4*4] = r;
  }
}

// ---------------- softmax over d=64 ----------------
__global__ __launch_bounds__(256)
void k_softmax(const float* __restrict__ EN, short* __restrict__ ATT){
  int row = blockIdx.x*4 + (threadIdx.x>>6);
  int lane = threadIdx.x & 63;
  float v = EN[(size_t)row*64 + lane];
  float m = v;
  #pragma unroll
  for (int s=1;s<64;s<<=1) m = fmaxf(m, __shfl_xor(m, s));
  float e = __expf(v - m);
  float sum = e;
  #pragma unroll
  for (int s=1;s<64;s<<=1) sum += __shfl_xor(sum, s);
  ATT[(size_t)row*64 + lane] = (short)bf16_rne(e / sum);
}

// ---------------- out = x + attn . Ke ----------------
__global__ __launch_bounds__(512)
void k_out(const float* __restrict__ x, const short* __restrict__ ATT,
           const short* __restrict__ KET, float* __restrict__ out){
  int nt = blockIdx.x, b = blockIdx.y;
  int n0 = nt*64;
  int tid = threadIdx.x, w = tid>>6, lane = tid&63;
  int lr = lane&15, lk = (lane>>4)<<3;
  f32x4 acc[4][4] = {};
  #pragma unroll
  for (int kt=0; kt<2; kt++){
    bf16x8 bb[4];
    #pragma unroll
    for (int j=0;j<4;j++)
      bb[j] = *(const bf16x8*)&KET[((size_t)(b*NPIX) + n0 + j*16 + lr)*64 + kt*32 + lk];
    #pragma unroll
    for (int r=0;r<4;r++){
      bf16x8 a = *(const bf16x8*)&ATT[((size_t)(b*CIN) + w*64 + r*16 + lr)*64 + kt*32 + lk];
      #pragma unroll
      for (int j=0;j<4;j++)
        acc[r][j] = MFMA(a, bb[j], acc[r][j]);
    }
  }
  int rq = (lane>>4)<<2;
  #pragma unroll
  for (int r=0;r<4;r++)
    #pragma unroll
    for (int j=0;j<4;j++){
      int col = n0 + j*16 + lr;
      #pragma unroll
      for (int q=0;q<4;q++){
        size_t idx = ((size_t)(b*CIN) + w*64 + r*16 + rq + q)*NPIX + col;
        out[idx] = x[idx] + acc[r][j][q];
      }
    }
}

extern "C" void kernel_launch(void* const* d_in, const int* in_sizes, int n_in,
                              void* d_out, int out_size, void* d_ws, size_t ws_size,
                              hipStream_t stream){
  const float* x   = (const float*)d_in[0];
  const float* Wq  = (const float*)d_in[1];
  const float* bq  = (const float*)d_in[2];
  const float* Wk  = (const float*)d_in[3];
  const float* bk  = (const float*)d_in[4];
  const float* Wv  = (const float*)d_in[5];
  const float* bv  = (const float*)d_in[6];
  const float* Wsq = (const float*)d_in[7];
  const float* bsq = (const float*)d_in[8];
  const float* We  = (const float*)d_in[9];
  const float* be  = (const float*)d_in[10];
  float* out = (float*)d_out;

  char* wsb = (char*)d_ws;
  size_t off = 0;
  auto alloc = [&](size_t bytes)->void*{
    void* p = wsb + off; off += (bytes + 255) & ~(size_t)255; return p;
  };
  short* WG   = (short*)alloc((size_t)512*512*2);
  short* WSE  = (short*)alloc((size_t)128*512*2);
  short* WSL  = (short*)alloc((size_t)64*512*2);
  float* BG   = (float*)alloc(512*4);
  float* BSE  = (float*)alloc(128*4);
  float* QSG  = (float*)alloc((size_t)BATCH*64*NPIX*4);
  short* KET  = (short*)alloc((size_t)BATCH*NPIX*64*2);
  float* Mb   = (float*)alloc((size_t)BATCH*512*64*4);
  float* Sb   = (float*)alloc((size_t)BATCH*64*4);
  float* EN   = (float*)alloc((size_t)BATCH*512*64*4);
  short* ATT  = (short*)alloc((size_t)BATCH*512*64*2);

  hipMemsetAsync(Mb, 0, (size_t)BATCH*512*64*4, stream);
  hipMemsetAsync(Sb, 0, (size_t)BATCH*64*4, stream);

  k_convw  <<<1024, 256, 0, stream>>>(Wq,bq,Wk,bk,Wsq,bsq,We,be, WG,WSE,WSL,BG,BSE);
  k_front  <<<dim3(32,16), 1024, 0, stream>>>(x, WG, BG, WSE, WSL, BSE, QSG, KET, Sb);
  k_M      <<<dim3(16,16), 512, 0, stream>>>(x, QSG, Mb);
  k_energy <<<dim3(16,16), 256, 0, stream>>>(Wv, bv, Mb, Sb, EN);
  k_softmax<<<2048, 256, 0, stream>>>(EN, ATT);
  k_out    <<<dim3(64,16), 512, 0, stream>>>(x, ATT, KET, out);
}

// Round 9
// 269.903 us; speedup vs baseline: 1.7693x; 1.7693x over previous
//
#include <hip/hip_runtime.h>

#define BATCH 16
#define CIN 512
#define NPIX 4096

typedef __attribute__((ext_vector_type(8))) short bf16x8;
typedef __attribute__((ext_vector_type(4))) float f32x4;

#define MFMA(a,b,c) __builtin_amdgcn_mfma_f32_16x16x32_bf16((a),(b),(c),0,0,0)

union PK  { short s[8]; bf16x8 v; };
union PK4 { short s[4]; uint2 u; };

__device__ __forceinline__ unsigned short bf16_rne(float f){
  unsigned u = __float_as_uint(f);
  return (unsigned short)((u + 0x7fffu + ((u >> 16) & 1u)) >> 16);
}
__device__ __forceinline__ void f32_split(float f, short &h, short &l){
  unsigned short hu = bf16_rne(f);
  h = (short)hu;
  float fh = __uint_as_float((unsigned)hu << 16);
  l = (short)bf16_rne(f - fh);
}
__device__ __forceinline__ void split8(float4 a, float4 b, bf16x8 &h, bf16x8 &l){
  float vv[8] = {a.x,a.y,a.z,a.w,b.x,b.y,b.z,b.w};
  PK ph, pl;
  #pragma unroll
  for (int z=0;z<8;z++){ short hh,ll; f32_split(vv[z],hh,ll); ph.s[z]=hh; pl.s[z]=ll; }
  h = ph.v; l = pl.v;
}

// chunk-XOR swizzle within a 512-short row: (row,k) -> row*512 + slot*8 + (k&7)
__device__ __forceinline__ int offBig(int row, int k){
  int s = k >> 3;
  s = (s & ~7) | ((s ^ row) & 7);
  return row*512 + s*8 + (k & 7);
}

// ---------------- weight convert ----------------
// WG  [512][512] bf16: row 2o = Wq[o], 2o+1 = Wk[o]
// WSE [128][512] bf16: rows 0-63 Ws, 64-127 We ; WSL [64][512] lo of Ws
__global__ __launch_bounds__(256)
void k_convw(const float* __restrict__ Wq, const float* __restrict__ bq,
             const float* __restrict__ Wk, const float* __restrict__ bk,
             const float* __restrict__ Ws, const float* __restrict__ bs,
             const float* __restrict__ We, const float* __restrict__ be,
             short* __restrict__ WG, short* __restrict__ WSE, short* __restrict__ WSL,
             float* __restrict__ BG, float* __restrict__ BSE){
  int t = blockIdx.x*256 + threadIdx.x;
  if (t < 512*512){
    int r = t >> 9, c = t & 511, o = r >> 1;
    float v = (r & 1) ? Wk[o*512+c] : Wq[o*512+c];
    WG[t] = (short)bf16_rne(v);
  }
  if (t < 128*512){
    int r = t >> 9, c = t & 511;
    float v = (r < 64) ? Ws[r*512+c] : We[(r-64)*512+c];
    short h,l; f32_split(v,h,l);
    WSE[t] = h;
    if (r < 64) WSL[t] = l;
  }
  if (t < 512) BG[t] = (t&1) ? bk[t>>1] : bq[t>>1];
  if (t < 128) BSE[t] = (t < 64) ? bs[t] : be[t-64];
}

// ---------------- fused front: gate + Qs(split,gate-folded) + Ke ----------------
// grid (64 nt, 16 b), 512 thr (8 waves). Single 64KB XS stage, fully-unrolled
// MLP staging (16 float4 loads in flight; rolled loop = 16 serialized HBM
// latencies = the R4-R7 ~150us mystery). (512,4): 2 blocks/CU so blocks
// overlap each other's stage/barrier phases. Separate gate/proj phases keep
// max live acc at 64 AGPR so 128-reg budget holds.
__global__ __launch_bounds__(512, 4)
void k_front(const float* __restrict__ x, const short* __restrict__ WG,
             const float* __restrict__ BG, const short* __restrict__ WSE,
             const short* __restrict__ WSL, const float* __restrict__ BSE,
             float* __restrict__ QSG, short* __restrict__ KET, float* __restrict__ S){
  __shared__ __align__(16) short XS[64*512];   // [n][c] bf16-hi, chunk-swizzled, 64 KB
  __shared__ float QKf[512];
  __shared__ float GF[64];
  int nt = blockIdx.x, b = blockIdx.y;
  int n0 = nt*64;
  int tid = threadIdx.x, w = tid>>6, lane = tid&63;
  int lr = lane&15, lk = (lane>>4)<<3;

  // stage: thread = channel c; ALL loads issued before any LDS write (MLP)
  {
    const float* xp = x + ((size_t)b*CIN + tid)*NPIX + n0;
    float4 vv[16];
    #pragma unroll
    for (int i=0;i<16;i++) vv[i] = *(const float4*)(xp + i*4);
    #pragma unroll
    for (int i=0;i<16;i++){
      float f[4] = {vv[i].x, vv[i].y, vv[i].z, vv[i].w};
      #pragma unroll
      for (int u=0;u<4;u++)
        XS[offBig(i*4+u, tid)] = (short)bf16_rne(f[u]);
    }
  }
  __syncthreads();

  int rq = (lane>>4)<<2;

  // ---- phase 1: gate GEMM (interleaved Q/K rows), A direct from global (L2) ----
  {
    const short* wgb = WG + (size_t)(w*64 + lr)*512 + lk;
    f32x4 acc[4][4] = {};
    for (int kt=0; kt<16; kt++){
      bf16x8 av[4];
      #pragma unroll
      for (int r=0;r<4;r++) av[r] = *(const bf16x8*)(wgb + r*16*512 + kt*32);
      bf16x8 bb[4];
      #pragma unroll
      for (int j=0;j<4;j++) bb[j] = *(const bf16x8*)&XS[offBig(j*16+lr, kt*32+lk)];
      #pragma unroll
      for (int r=0;r<4;r++)
        #pragma unroll
        for (int j=0;j<4;j++)
          acc[r][j] = MFMA(av[r], bb[j], acc[r][j]);
    }
    float p[4] = {0.f,0.f,0.f,0.f};
    #pragma unroll
    for (int r=0;r<4;r++){
      f32x4 bg = *(const f32x4*)&BG[w*64 + r*16 + rq];
      #pragma unroll
      for (int j=0;j<4;j++){
        f32x4 a4 = acc[r][j];
        p[j] += (a4[0]+bg[0])*(a4[1]+bg[1]) + (a4[2]+bg[2])*(a4[3]+bg[3]);
      }
    }
    #pragma unroll
    for (int j=0;j<4;j++){ p[j] += __shfl_xor(p[j],16); p[j] += __shfl_xor(p[j],32); }
    if (lane < 16){
      #pragma unroll
      for (int j=0;j<4;j++) QKf[w*64 + j*16 + lane] = p[j];
    }
  }
  __syncthreads();
  if (tid < 64){
    float s = 0.f;
    #pragma unroll
    for (int ww=0;ww<8;ww++) s += QKf[ww*64 + tid];
    GF[tid] = 1.f/(1.f + __expf(-s*(1.f/256.f)));
  }
  __syncthreads();

  // ---- phase 2: Qs (waves 0-3, hi+lo) and Ke (waves 4-7) ----
  bool isQs = (w < 4);
  const short* wb  = WSE + (size_t)((isQs ? (w*16) : (64 + (w-4)*16)) + lr)*512 + lk;
  const short* wlb = WSL + (size_t)((isQs ? (w*16) : 0) + lr)*512 + lk;
  f32x4 acc2[4] = {};
  for (int kt=0; kt<16; kt++){
    bf16x8 bb[4];
    #pragma unroll
    for (int j=0;j<4;j++) bb[j] = *(const bf16x8*)&XS[offBig(j*16+lr, kt*32+lk)];
    bf16x8 ah = *(const bf16x8*)(wb + kt*32);
    if (isQs){
      bf16x8 al = *(const bf16x8*)(wlb + kt*32);
      #pragma unroll
      for (int j=0;j<4;j++){
        acc2[j] = MFMA(al, bb[j], acc2[j]);
        acc2[j] = MFMA(ah, bb[j], acc2[j]);
      }
    } else {
      #pragma unroll
      for (int j=0;j<4;j++)
        acc2[j] = MFMA(ah, bb[j], acc2[j]);
    }
  }

  // ---- epilogue ----
  if (isQs){
    int row0 = w*16 + rq;
    f32x4 bs4 = *(const f32x4*)&BSE[row0];
    float srow[4] = {0.f,0.f,0.f,0.f};
    #pragma unroll
    for (int j=0;j<4;j++){
      int nl = j*16 + lr;
      float g = GF[nl];
      int n = n0 + nl;
      #pragma unroll
      for (int q=0;q<4;q++){
        float v = (acc2[j][q] + bs4[q]) * g;
        QSG[((size_t)(b*64) + row0 + q)*NPIX + n] = v;
        srow[q] += v;
      }
    }
    #pragma unroll
    for (int q=0;q<4;q++){
      float v = srow[q];
      v += __shfl_xor(v,1); v += __shfl_xor(v,2);
      v += __shfl_xor(v,4); v += __shfl_xor(v,8);
      if (lr == 0) atomicAdd(&S[b*64 + row0 + q], v);
    }
  } else {
    int d0 = (w-4)*16 + rq;
    f32x4 be4 = *(const f32x4*)&BSE[64 + d0];
    #pragma unroll
    for (int j=0;j<4;j++){
      int n = n0 + j*16 + lr;
      PK4 pk;
      #pragma unroll
      for (int q=0;q<4;q++) pk.s[q] = (short)bf16_rne(acc2[j][q] + be4[q]);
      *(uint2*)&KET[((size_t)(b*NPIX) + n)*64 + d0] = pk.u;
    }
  }
}

// ---------------- M[b][512][64] += x . QSG^T over n (reg-split, no LDS) ----------------
// 16 slabs x 256 n: halves atomic traffic vs 32 slabs.
__global__ __launch_bounds__(512)
void k_M(const float* __restrict__ x, const float* __restrict__ QSG,
         float* __restrict__ M){
  int slab = blockIdx.x, b = blockIdx.y;
  int tid = threadIdx.x, w = tid>>6, lane = tid&63;
  int lr = lane&15, lk8 = (lane>>4)<<3;
  f32x4 acc[4][4] = {};
  for (int kt=0; kt<8; kt++){
    int noff = slab*256 + kt*32 + lk8;
    bf16x8 bh[4], bl[4];
    #pragma unroll
    for (int j=0;j<4;j++){
      const float* qp = QSG + ((size_t)(b*64) + j*16 + lr)*NPIX + noff;
      split8(*(const float4*)qp, *(const float4*)(qp+4), bh[j], bl[j]);
    }
    #pragma unroll
    for (int r=0;r<4;r++){
      const float* xp = x + ((size_t)(b*CIN) + w*64 + r*16 + lr)*NPIX + noff;
      bf16x8 ah, al;
      split8(*(const float4*)xp, *(const float4*)(xp+4), ah, al);
      #pragma unroll
      for (int j=0;j<4;j++){
        acc[r][j] = MFMA(al, bh[j], acc[r][j]);
        acc[r][j] = MFMA(ah, bl[j], acc[r][j]);
        acc[r][j] = MFMA(ah, bh[j], acc[r][j]);
      }
    }
  }
  int rq = (lane>>4)<<2;
  #pragma unroll
  for (int r=0;r<4;r++)
    #pragma unroll
    for (int j=0;j<4;j++)
      #pragma unroll
      for (int q=0;q<4;q++)
        atomicAdd(&M[((size_t)(b*CIN) + w*64 + r*16 + rq + q)*64 + j*16 + lr], acc[r][j][q]);
}

// ---------------- energy = Wv(f32) . M + bv*S  (VALU, exact) ----------------
__global__ __launch_bounds__(256)
void k_energy(const float* __restrict__ Wv, const float* __restrict__ bv,
              const float* __restrict__ M, const float* __restrict__ S,
              float* __restrict__ EN){
  __shared__ __align__(16) float ML[128*68];
  int cch = blockIdx.x, b = blockIdx.y;
  int tid = threadIdx.x;
  int d4 = tid & 15, ci = tid >> 4;
  f32x4 acc[2] = {};
  for (int kt=0; kt<4; kt++){
    __syncthreads();
    for (int i = tid; i < 2048; i += 256){
      int k = i >> 4, c4 = (i & 15) * 4;
      *(float4*)&ML[k*68 + c4] = *(const float4*)&M[((size_t)(b*CIN) + kt*128 + k)*64 + c4];
    }
    __syncthreads();
    #pragma unroll
    for (int m=0;m<2;m++){
      int c = cch*32 + ci + 16*m;
      const float* wvp = Wv + (size_t)c*512 + kt*128;
      for (int k4=0;k4<32;k4++){
        float4 wv4 = *(const float4*)(wvp + k4*4);
        f32x4 m0 = *(const f32x4*)&ML[(k4*4+0)*68 + d4*4];
        f32x4 m1 = *(const f32x4*)&ML[(k4*4+1)*68 + d4*4];
        f32x4 m2 = *(const f32x4*)&ML[(k4*4+2)*68 + d4*4];
        f32x4 m3 = *(const f32x4*)&ML[(k4*4+3)*68 + d4*4];
        acc[m] += m0*wv4.x + m1*wv4.y + m2*wv4.z + m3*wv4.w;
      }
    }
  }
  f32x4 s4 = *(const f32x4*)&S[b*64 + d4*4];
  #pragma unroll
  for (int m=0;m<2;m++){
    int c = cch*32 + ci + 16*m;
    f32x4 r = acc[m] + s4*bv[c];
    *(f32x4*)&EN[((size_t)(b*CIN) + c)*64 + d4*4] = r;
  }
}

// ---------------- softmax over d=64 ----------------
__global__ __launch_bounds__(256)
void k_softmax(const float* __restrict__ EN, short* __restrict__ ATT){
  int row = blockIdx.x*4 + (threadIdx.x>>6);
  int lane = threadIdx.x & 63;
  float v = EN[(size_t)row*64 + lane];
  float m = v;
  #pragma unroll
  for (int s=1;s<64;s<<=1) m = fmaxf(m, __shfl_xor(m, s));
  float e = __expf(v - m);
  float sum = e;
  #pragma unroll
  for (int s=1;s<64;s<<=1) sum += __shfl_xor(sum, s);
  ATT[(size_t)row*64 + lane] = (short)bf16_rne(e / sum);
}

// ---------------- out = x + attn . Ke ----------------
__global__ __launch_bounds__(512)
void k_out(const float* __restrict__ x, const short* __restrict__ ATT,
           const short* __restrict__ KET, float* __restrict__ out){
  int nt = blockIdx.x, b = blockIdx.y;
  int n0 = nt*64;
  int tid = threadIdx.x, w = tid>>6, lane = tid&63;
  int lr = lane&15, lk = (lane>>4)<<3;
  f32x4 acc[4][4] = {};
  #pragma unroll
  for (int kt=0; kt<2; kt++){
    bf16x8 bb[4];
    #pragma unroll
    for (int j=0;j<4;j++)
      bb[j] = *(const bf16x8*)&KET[((size_t)(b*NPIX) + n0 + j*16 + lr)*64 + kt*32 + lk];
    #pragma unroll
    for (int r=0;r<4;r++){
      bf16x8 a = *(const bf16x8*)&ATT[((size_t)(b*CIN) + w*64 + r*16 + lr)*64 + kt*32 + lk];
      #pragma unroll
      for (int j=0;j<4;j++)
        acc[r][j] = MFMA(a, bb[j], acc[r][j]);
    }
  }
  int rq = (lane>>4)<<2;
  #pragma unroll
  for (int r=0;r<4;r++)
    #pragma unroll
    for (int j=0;j<4;j++){
      int col = n0 + j*16 + lr;
      #pragma unroll
      for (int q=0;q<4;q++){
        size_t idx = ((size_t)(b*CIN) + w*64 + r*16 + rq + q)*NPIX + col;
        out[idx] = x[idx] + acc[r][j][q];
      }
    }
}

extern "C" void kernel_launch(void* const* d_in, const int* in_sizes, int n_in,
                              void* d_out, int out_size, void* d_ws, size_t ws_size,
                              hipStream_t stream){
  const float* x   = (const float*)d_in[0];
  const float* Wq  = (const float*)d_in[1];
  const float* bq  = (const float*)d_in[2];
  const float* Wk  = (const float*)d_in[3];
  const float* bk  = (const float*)d_in[4];
  const float* Wv  = (const float*)d_in[5];
  const float* bv  = (const float*)d_in[6];
  const float* Wsq = (const float*)d_in[7];
  const float* bsq = (const float*)d_in[8];
  const float* We  = (const float*)d_in[9];
  const float* be  = (const float*)d_in[10];
  float* out = (float*)d_out;

  char* wsb = (char*)d_ws;
  size_t off = 0;
  auto alloc = [&](size_t bytes)->void*{
    void* p = wsb + off; off += (bytes + 255) & ~(size_t)255; return p;
  };
  short* WG   = (short*)alloc((size_t)512*512*2);
  short* WSE  = (short*)alloc((size_t)128*512*2);
  short* WSL  = (short*)alloc((size_t)64*512*2);
  float* BG   = (float*)alloc(512*4);
  float* BSE  = (float*)alloc(128*4);
  float* QSG  = (float*)alloc((size_t)BATCH*64*NPIX*4);
  short* KET  = (short*)alloc((size_t)BATCH*NPIX*64*2);
  float* Mb   = (float*)alloc((size_t)BATCH*512*64*4);
  float* Sb   = (float*)alloc((size_t)BATCH*64*4);
  float* EN   = (float*)alloc((size_t)BATCH*512*64*4);
  short* ATT  = (short*)alloc((size_t)BATCH*512*64*2);

  hipMemsetAsync(Mb, 0, (size_t)BATCH*512*64*4, stream);
  hipMemsetAsync(Sb, 0, (size_t)BATCH*64*4, stream);

  k_convw  <<<1024, 256, 0, stream>>>(Wq,bq,Wk,bk,Wsq,bsq,We,be, WG,WSE,WSL,BG,BSE);
  k_front  <<<dim3(64,16), 512, 0, stream>>>(x, WG, BG, WSE, WSL, BSE, QSG, KET, Sb);
  k_M      <<<dim3(16,16), 512, 0, stream>>>(x, QSG, Mb);
  k_energy <<<dim3(16,16), 256, 0, stream>>>(Wv, bv, Mb, Sb, EN);
  k_softmax<<<2048, 256, 0, stream>>>(EN, ATT);
  k_out    <<<dim3(64,16), 512, 0, stream>>>(x, ATT, KET, out);
}